// Round 2
// baseline (120.117 us; speedup 1.0000x reference)
//
#include <hip/hip_runtime.h>
#include <math.h>

#define Bp 256
#define Tp 128
#define SDp 8
#define ADp 2
#define Hp 3
#define Kp 4
#define HIDp 256
#define QDp (SDp + ADp)       // 10
#define X1Dp (Hp * Kp + QDp)  // 22
#define X1LD 40               // X1s row stride in shorts (80 B, 16B-aligned rows)
#define LOG2E 1.4426950408889634f

typedef short bf16x8 __attribute__((ext_vector_type(8)));
typedef float f32x4  __attribute__((ext_vector_type(4)));

__device__ __forceinline__ unsigned short f2bf(float f) {
    unsigned u = __float_as_uint(f);
    unsigned r = (u + 0x7FFFu + ((u >> 16) & 1u)) >> 16;
    return (unsigned short)r;
}

// h1 LDS addressing: row stride 512 B, XOR-swizzle bits 4-6 with row&7 (T2)
__device__ __forceinline__ unsigned h1_byte(int row, int col2bytes) {
    unsigned off = ((unsigned)row << 9) + (unsigned)col2bytes;
    return off ^ ((unsigned)(row & 7) << 4);
}

// ---------------------------------------------------------------------------
// prep: one-time W1/W2 f32 -> bf16 conversion into workspace.
//   blocks [0,64):  W2b[i] (65536 elems, float4/thread)
//   blocks [64,96): W1b (256 rows x 32 padded cols; cols >=22 zero)
// ---------------------------------------------------------------------------
__global__ __launch_bounds__(256) void prep_kernel(
    const float* __restrict__ W1, const float* __restrict__ W2,
    unsigned short* __restrict__ W1b, unsigned short* __restrict__ W2b)
{
    const int bid = blockIdx.x;
    if (bid < 64) {
        const int i = (bid * 256 + threadIdx.x) * 4;
        const float4 v = *(const float4*)(W2 + i);
        ushort4 o;
        o.x = f2bf(v.x); o.y = f2bf(v.y); o.z = f2bf(v.z); o.w = f2bf(v.w);
        *(ushort4*)(W2b + i) = o;
    } else {
        const int i = (bid - 64) * 256 + threadIdx.x;   // 0..8191
        const int r = i >> 5, c = i & 31;
        W1b[i] = (c < X1Dp) ? f2bf(W1[r * X1Dp + c]) : (unsigned short)0;
    }
}

// ---------------------------------------------------------------------------
// main: 512 blocks x 256 threads; block = (batch, half) -> 64 positions.
// Phase A  attention: pos = wave*16 + l16, jq = quad covers 32 j's;
//          combine via shfl_xor(16,32); finalize split over quads; X1 -> LDS.
// Phase B  MLP1 MFMA: wave w = row-tile w; B-frags from W1b (global, L2-hot);
//          h1 -> LDS (bf16, XOR-swizzled).
// Phase C  MLP2: wave w owns output cols [w*64, w*64+64); A-frags (all 4 row
//          tiles) resident in VGPRs; B-frags from W2b (global, read once per
//          block); relu+Wout reduce in-register; cross-wave via partial[] LDS.
// LDS ~42 KB -> 2 blocks/CU resident (grid 512 = 2/CU): phases overlap
// across blocks.
// ---------------------------------------------------------------------------
__global__ __launch_bounds__(256, 2) void main_kernel(
    const float* __restrict__ state, const float* __restrict__ action,
    const float* __restrict__ Wk, const float* __restrict__ Wq,
    const float* __restrict__ Wv,
    const unsigned short* __restrict__ W1b, const unsigned short* __restrict__ W2b,
    const float* __restrict__ b1, const float* __restrict__ b2,
    const float* __restrict__ Wout, const float* __restrict__ bout,
    float* __restrict__ out)
{
    const int bid   = blockIdx.x;
    const int batch = bid >> 1;
    const int t0    = (bid & 1) * 64;
    const int tid   = threadIdx.x;
    const int lane  = tid & 63;
    const int wave  = tid >> 6;     // 0..3
    const int l16   = lane & 15;
    const int quad  = lane >> 4;    // phase A: jq; phases B/C: K-chunk
    const int pos   = wave * 16 + l16;   // 0..63 (block-local position)
    const int t     = t0 + pos;          // global position in batch

    __shared__ float4 s4[Tp];                              // 2 KB
    __shared__ float  wq[Hp * Kp * QDp];                   // 480 B
    __shared__ float  wk[Hp * Kp * Kp];                    // 192 B
    __shared__ float  wv[Hp * Kp * Kp];                    // 192 B
    __shared__ __align__(16) unsigned short X1s[64 * X1LD];   // 5 KB
    __shared__ __align__(16) unsigned short h1s[64 * 256];    // 32 KB, swizzled
    __shared__ __align__(16) float partial[4][64];            // 1 KB

    // ---- stage batch state + small weights ----
    if (tid < Tp)
        s4[tid] = ((const float4*)(state + (size_t)batch * Tp * SDp))[tid * 2];
    if (tid >= Tp && tid < Tp + Hp * Kp * QDp)
        wq[tid - Tp] = Wq[tid - Tp];
    if (tid < Hp * Kp * Kp) { wk[tid] = Wk[tid]; wv[tid] = Wv[tid]; }
    __syncthreads();

    // ---- phase A: attention ----
    float qs[QDp];
    {
        const float* srow = state + ((size_t)batch * Tp + t) * SDp;
        #pragma unroll
        for (int d = 0; d < SDp; ++d) qs[d] = srow[d];
        const float* arow = action + ((size_t)batch * Tp + t) * ADp;
        qs[8] = arow[0]; qs[9] = arow[1];
    }

    float q[Hp * Kp];
    #pragma unroll
    for (int r = 0; r < Hp * Kp; ++r) {
        float a = 0.f;
        #pragma unroll
        for (int d = 0; d < QDp; ++d) a += qs[d] * wq[r * QDp + d];
        q[r] = a;
    }
    float qkp[Hp * Kp];   // (0.5*log2e) * q @ Wk  (exp -> exp2 fold)
    #pragma unroll
    for (int h = 0; h < Hp; ++h)
        #pragma unroll
        for (int c = 0; c < Kp; ++c) {
            float a = 0.f;
            #pragma unroll
            for (int k = 0; k < Kp; ++k) a += q[h * Kp + k] * wk[(h * Kp + k) * Kp + c];
            qkp[h * Kp + c] = 0.5f * LOG2E * a;
        }

    const float4 st = s4[t];
    float ch0[Hp];
    #pragma unroll
    for (int h = 0; h < Hp; ++h)
        ch0[h] = st.x * qkp[h*4] + st.y * qkp[h*4+1] + st.z * qkp[h*4+2] + st.w * qkp[h*4+3];

    float l[Hp] = {0.f, 0.f, 0.f};
    float accs[Hp][4] = {};
    const int j0 = quad * 32;
    for (int j = j0; j < j0 + 32; ++j) {
        const float4 sj = s4[j];
        #pragma unroll
        for (int h = 0; h < Hp; ++h) {
            const float d = sj.x * qkp[h*4] + sj.y * qkp[h*4+1]
                          + sj.z * qkp[h*4+2] + sj.w * qkp[h*4+3] - ch0[h];
            const float e = (j == t) ? 0.f : exp2f(d);
            l[h] += e;
            accs[h][0] += e * sj.x; accs[h][1] += e * sj.y;
            accs[h][2] += e * sj.z; accs[h][3] += e * sj.w;
        }
    }
    // combine the 4 j-quarters (lanes differing in bits 4,5)
    #pragma unroll
    for (int h = 0; h < Hp; ++h) {
        l[h] += __shfl_xor(l[h], 16); l[h] += __shfl_xor(l[h], 32);
        #pragma unroll
        for (int c = 0; c < Kp; ++c) {
            accs[h][c] += __shfl_xor(accs[h][c], 16);
            accs[h][c] += __shfl_xor(accs[h][c], 32);
        }
    }

    // finalize: quads 0..2 -> head h = quad (x cols 4h..4h+3); quad 3 -> q_state+pad
    if (quad < Hp) {
        const int h = quad;
        const float inv = 1.f / l[h];
        const float rb0 = accs[h][0] * inv - st.x;
        const float rb1 = accs[h][1] * inv - st.y;
        const float rb2 = accs[h][2] * inv - st.z;
        const float rb3 = accs[h][3] * inv - st.w;
        ushort4 o;
        {
            const int r0 = h * Kp;
            o.x = f2bf(rb0*wv[(r0+0)*4] + rb1*wv[(r0+0)*4+1] + rb2*wv[(r0+0)*4+2] + rb3*wv[(r0+0)*4+3]);
            o.y = f2bf(rb0*wv[(r0+1)*4] + rb1*wv[(r0+1)*4+1] + rb2*wv[(r0+1)*4+2] + rb3*wv[(r0+1)*4+3]);
            o.z = f2bf(rb0*wv[(r0+2)*4] + rb1*wv[(r0+2)*4+1] + rb2*wv[(r0+2)*4+2] + rb3*wv[(r0+2)*4+3]);
            o.w = f2bf(rb0*wv[(r0+3)*4] + rb1*wv[(r0+3)*4+1] + rb2*wv[(r0+3)*4+2] + rb3*wv[(r0+3)*4+3]);
        }
        *(ushort4*)&X1s[pos * X1LD + h * 4] = o;      // byte 80*pos + 8h: 8B-aligned
    } else {
        // cols 12..31: q_state (10) + zeros (10) as five 8-byte stores
        uint2 d[5];
        d[0].x = (unsigned)f2bf(qs[0]) | ((unsigned)f2bf(qs[1]) << 16);
        d[0].y = (unsigned)f2bf(qs[2]) | ((unsigned)f2bf(qs[3]) << 16);
        d[1].x = (unsigned)f2bf(qs[4]) | ((unsigned)f2bf(qs[5]) << 16);
        d[1].y = (unsigned)f2bf(qs[6]) | ((unsigned)f2bf(qs[7]) << 16);
        d[2].x = (unsigned)f2bf(qs[8]) | ((unsigned)f2bf(qs[9]) << 16);
        d[2].y = 0u; d[3].x = 0u; d[3].y = 0u; d[4].x = 0u; d[4].y = 0u;
        uint2* dst = (uint2*)&X1s[pos * X1LD + 12];   // byte 80*pos + 24: 8B-aligned
        #pragma unroll
        for (int i = 0; i < 5; ++i) dst[i] = d[i];
    }
    __syncthreads();

    // ---- phase B: MLP1 (wave = row-tile) ----
    {
        const bf16x8 afr = *(const bf16x8*)&X1s[pos * X1LD + quad * 8];
        for (int nt = 0; nt < 16; ++nt) {
            const bf16x8 bfr = *(const bf16x8*)&W1b[(nt * 16 + l16) * 32 + quad * 8];
            f32x4 acc = {0.f, 0.f, 0.f, 0.f};
            acc = __builtin_amdgcn_mfma_f32_16x16x32_bf16(afr, bfr, acc, 0, 0, 0);
            const int col = nt * 16 + l16;
            const float bb = b1[col];
            #pragma unroll
            for (int r = 0; r < 4; ++r) {
                const int row = wave * 16 + quad * 4 + r;
                *(unsigned short*)((char*)h1s + h1_byte(row, col * 2)) =
                    f2bf(fmaxf(acc[r] + bb, 0.f));
            }
        }
    }
    __syncthreads();

    // ---- phase C: MLP2 + out (wave owns cols [wave*64, wave*64+64)) ----
    bf16x8 A[4][8];
    #pragma unroll
    for (int rt = 0; rt < 4; ++rt)
        #pragma unroll
        for (int ks = 0; ks < 8; ++ks) {
            const int row = rt * 16 + l16;
            A[rt][ks] = *(const bf16x8*)((const char*)h1s + h1_byte(row, ks * 64 + quad * 16));
        }

    float rsum[4][4] = {};
    #pragma unroll 1
    for (int i = 0; i < 4; ++i) {
        const int nt  = wave * 4 + i;
        const int col = nt * 16 + l16;
        const unsigned short* wr = W2b + (size_t)col * HIDp + quad * 8;
        bf16x8 Bf[8];
        #pragma unroll
        for (int ks = 0; ks < 8; ++ks)
            Bf[ks] = *(const bf16x8*)(wr + ks * 32);
        const float bb = b2[col];
        const float wo = Wout[col];
        #pragma unroll
        for (int rt = 0; rt < 4; ++rt) {
            f32x4 acc = {0.f, 0.f, 0.f, 0.f};
            #pragma unroll
            for (int ks = 0; ks < 8; ++ks)
                acc = __builtin_amdgcn_mfma_f32_16x16x32_bf16(A[rt][ks], Bf[ks], acc, 0, 0, 0);
            #pragma unroll
            for (int r = 0; r < 4; ++r)
                rsum[rt][r] += fmaxf(acc[r] + bb, 0.f) * wo;
        }
    }

    // reduce over the 16 cols held across l16
    #pragma unroll
    for (int off = 1; off < 16; off <<= 1)
        #pragma unroll
        for (int rt = 0; rt < 4; ++rt)
            #pragma unroll
            for (int r = 0; r < 4; ++r)
                rsum[rt][r] += __shfl_xor(rsum[rt][r], off);

    if (l16 == 0) {
        #pragma unroll
        for (int rt = 0; rt < 4; ++rt) {
            f32x4 v = {rsum[rt][0], rsum[rt][1], rsum[rt][2], rsum[rt][3]};
            *(f32x4*)&partial[wave][rt * 16 + quad * 4] = v;
        }
    }
    __syncthreads();

    if (tid < 64) {
        const float o = partial[0][tid] + partial[1][tid] + partial[2][tid]
                      + partial[3][tid] + bout[0];
        out[(size_t)batch * Tp + t0 + tid] = o;
    }
}

extern "C" void kernel_launch(void* const* d_in, const int* in_sizes, int n_in,
                              void* d_out, int out_size, void* d_ws, size_t ws_size,
                              hipStream_t stream) {
    const float* state  = (const float*)d_in[0];
    const float* action = (const float*)d_in[1];
    const float* Wk     = (const float*)d_in[2];
    const float* Wq     = (const float*)d_in[3];
    const float* Wv     = (const float*)d_in[4];
    const float* W1     = (const float*)d_in[5];
    const float* b1     = (const float*)d_in[6];
    const float* W2     = (const float*)d_in[7];
    const float* b2     = (const float*)d_in[8];
    const float* Wout   = (const float*)d_in[9];
    const float* bout   = (const float*)d_in[10];
    float* out = (float*)d_out;

    char* ws = (char*)d_ws;
    unsigned short* W1b = (unsigned short*)(ws);           // 16 KB
    unsigned short* W2b = (unsigned short*)(ws + 16384);   // 128 KB

    prep_kernel<<<96, 256, 0, stream>>>(W1, W2, W1b, W2b);
    main_kernel<<<2 * Bp, 256, 0, stream>>>(state, action, Wk, Wq, Wv,
                                            W1b, W2b, b1, b2, Wout, bout, out);
}

// Round 3
// 101.347 us; speedup vs baseline: 1.1852x; 1.1852x over previous
//
#include <hip/hip_runtime.h>
#include <math.h>

#define Bp 256
#define Tp 128
#define SDp 8
#define ADp 2
#define Hp 3
#define Kp 4
#define HIDp 256
#define QDp (SDp + ADp)       // 10
#define X1Dp (Hp * Kp + QDp)  // 22  (row padded to 32 bf16 = 64 B)
#define QKLD 20               // qk LDS row stride (floats): (t*5+k)%8 distinct -> conflict-free
#define LOG2E 1.4426950408889634f

typedef short bf16x8 __attribute__((ext_vector_type(8)));
typedef float f32x4  __attribute__((ext_vector_type(4)));

__device__ __forceinline__ unsigned short f2bf(float f) {
    unsigned u = __float_as_uint(f);
    unsigned r = (u + 0x7FFFu + ((u >> 16) & 1u)) >> 16;
    return (unsigned short)r;
}

// h1 LDS: row stride 512 B, XOR bits 4-6 with row&7 -> conflict-free b128 col reads
__device__ __forceinline__ unsigned h1_byte(int row, int colbytes) {
    return (((unsigned)row << 9) + (unsigned)colbytes) ^ ((unsigned)(row & 7) << 4);
}

// ---------------------------------------------------------------------------
// attn+prep: blocks [0,1024) = attention (32 positions x 8-way j-split);
//            blocks [1024,1120) = one-time W1/W2 f32->bf16 prep.
// Attention thread layout: tid = t_loc*8 + jo  (t_loc in [0,32), jo in [0,8)).
//  - 32 threads precompute qkp/ch (+ bf16 q_state) per t into LDS qk[].
//  - j-loop: 16 iters, j = jo*16 + ((i+jo)&15)  (rotation -> 8 distinct bank
//    octets across jo -> conflict-free s4 reads).
//  - combine jo-partials via shfl_xor(1,2,4); jo==0 lanes finalize + write X1b.
// ---------------------------------------------------------------------------
__global__ __launch_bounds__(256, 4) void attn_prep_kernel(
    const float* __restrict__ state, const float* __restrict__ action,
    const float* __restrict__ Wk, const float* __restrict__ Wq,
    const float* __restrict__ Wv, const float* __restrict__ W1,
    const float* __restrict__ W2, unsigned short* __restrict__ W1b,
    unsigned short* __restrict__ W2b, unsigned short* __restrict__ X1b)
{
    const int tid = threadIdx.x;
    if (blockIdx.x >= 1024) {
        const int pb = blockIdx.x - 1024;
        if (pb < 64) {                       // W2 -> bf16 (65536 elems)
            const int i = pb * 1024 + tid * 4;
            const float4 v = *(const float4*)(W2 + i);
            ushort4 o;
            o.x = f2bf(v.x); o.y = f2bf(v.y); o.z = f2bf(v.z); o.w = f2bf(v.w);
            *(ushort4*)(W2b + i) = o;
        } else {                             // W1 -> bf16, 32-col padded rows
            const int i = (pb - 64) * 256 + tid;   // 0..8191
            const int r = i >> 5, c = i & 31;
            W1b[i] = (c < X1Dp) ? f2bf(W1[r * X1Dp + c]) : (unsigned short)0;
        }
        return;
    }

    const int bid   = blockIdx.x;
    const int batch = bid >> 2;
    const int t0    = (bid & 3) * 32;
    const int t_loc = tid >> 3;
    const int jo    = tid & 7;
    const int t     = t0 + t_loc;

    __shared__ float4 s4[Tp];              // 2 KB: state[:, :, :4] for this batch
    __shared__ float  wq[Hp * Kp * QDp];   // 480 B
    __shared__ float  wk[Hp * Kp * Kp];    // 192 B
    __shared__ float  wv[Hp * Kp * Kp];    // 192 B
    __shared__ float  qk[32 * QKLD];       // per-t: qkp[12], ch[3], qs-bf16 [5], 2.5 KB

    if (tid < Tp)
        s4[tid] = ((const float4*)(state + (size_t)batch * Tp * SDp))[tid * 2];
    if (tid >= Tp && tid < Tp + Hp * Kp * QDp)
        wq[tid - Tp] = Wq[tid - Tp];
    if (tid < Hp * Kp * Kp) { wk[tid] = Wk[tid]; wv[tid] = Wv[tid]; }
    __syncthreads();

    // ---- per-t precompute (32 threads) ----
    if (tid < 32) {
        const int tt = t0 + tid;
        const float* srow = state + ((size_t)batch * Tp + tt) * SDp;
        float qs[QDp];
        {
            const float4 v0 = *(const float4*)srow;
            const float4 v1 = *(const float4*)(srow + 4);
            qs[0]=v0.x; qs[1]=v0.y; qs[2]=v0.z; qs[3]=v0.w;
            qs[4]=v1.x; qs[5]=v1.y; qs[6]=v1.z; qs[7]=v1.w;
            const float* arow = action + ((size_t)batch * Tp + tt) * ADp;
            qs[8] = arow[0]; qs[9] = arow[1];
        }
        float q[Hp * Kp];
        #pragma unroll
        for (int r = 0; r < Hp * Kp; ++r) {
            float a = 0.f;
            #pragma unroll
            for (int d = 0; d < QDp; ++d) a += qs[d] * wq[r * QDp + d];
            q[r] = a;
        }
        float* qrow = &qk[tid * QKLD];
        const float4 st = s4[tt];
        #pragma unroll
        for (int h = 0; h < Hp; ++h) {
            float p[4];
            #pragma unroll
            for (int c = 0; c < Kp; ++c) {
                float a = 0.f;
                #pragma unroll
                for (int k = 0; k < Kp; ++k) a += q[h * Kp + k] * wk[(h * Kp + k) * Kp + c];
                p[c] = 0.5f * LOG2E * a;
                qrow[h * 4 + c] = p[c];
            }
            qrow[12 + h] = st.x * p[0] + st.y * p[1] + st.z * p[2] + st.w * p[3];
        }
        #pragma unroll
        for (int i = 0; i < 5; ++i) {
            const unsigned u = (unsigned)f2bf(qs[2*i]) | ((unsigned)f2bf(qs[2*i+1]) << 16);
            qrow[15 + i] = __uint_as_float(u);
        }
    }
    __syncthreads();

    // ---- j-loop (all 256 threads) ----
    float rq[20];
    #pragma unroll
    for (int i = 0; i < 5; ++i)
        *(float4*)&rq[i * 4] = *(const float4*)&qk[t_loc * QKLD + i * 4];

    float l[Hp] = {0.f, 0.f, 0.f};
    float ac[Hp][4] = {};
    #pragma unroll
    for (int i = 0; i < 16; ++i) {
        const int j = (jo << 4) | ((i + jo) & 15);   // rotated: conflict-free banks
        const float4 sj = s4[j];
        #pragma unroll
        for (int h = 0; h < Hp; ++h) {
            const float d = sj.x * rq[h*4] + sj.y * rq[h*4+1]
                          + sj.z * rq[h*4+2] + sj.w * rq[h*4+3] - rq[12 + h];
            const float e = (j == t) ? 0.f : __builtin_amdgcn_exp2f(d);
            l[h] += e;
            ac[h][0] += e * sj.x; ac[h][1] += e * sj.y;
            ac[h][2] += e * sj.z; ac[h][3] += e * sj.w;
        }
    }
    #pragma unroll
    for (int off = 1; off < 8; off <<= 1) {
        #pragma unroll
        for (int h = 0; h < Hp; ++h) {
            l[h] += __shfl_xor(l[h], off);
            #pragma unroll
            for (int c = 0; c < Kp; ++c) ac[h][c] += __shfl_xor(ac[h][c], off);
        }
    }

    if (jo == 0) {
        const float4 st = s4[t];
        unsigned short rowb[32] __attribute__((aligned(16)));
        #pragma unroll
        for (int h = 0; h < Hp; ++h) {
            const float inv = 1.f / l[h];
            const float rb0 = ac[h][0] * inv - st.x;
            const float rb1 = ac[h][1] * inv - st.y;
            const float rb2 = ac[h][2] * inv - st.z;
            const float rb3 = ac[h][3] * inv - st.w;
            #pragma unroll
            for (int k = 0; k < Kp; ++k) {
                const int r = h * Kp + k;
                rowb[r] = f2bf(rb0 * wv[r*4] + rb1 * wv[r*4+1] + rb2 * wv[r*4+2] + rb3 * wv[r*4+3]);
            }
        }
        #pragma unroll
        for (int i = 0; i < 5; ++i) {
            const unsigned u = __float_as_uint(rq[15 + i]);
            rowb[12 + 2*i] = (unsigned short)(u & 0xffffu);
            rowb[13 + 2*i] = (unsigned short)(u >> 16);
        }
        #pragma unroll
        for (int i = X1Dp; i < 32; ++i) rowb[i] = 0;

        uint4* dst = (uint4*)(X1b + ((size_t)batch * Tp + t) * 32);
        const uint4* srcv = (const uint4*)rowb;
        #pragma unroll
        for (int i = 0; i < 4; ++i) dst[i] = srcv[i];
    }
}

// ---------------------------------------------------------------------------
// mlp: 1024 blocks x 256 threads, 32 positions/block. LDS 16.5 KB.
// MLP1: wave w -> row-tile (w&1), col-half (w>>1); h1 bf16 -> swizzled LDS.
// MLP2: wave w owns cols [w*64, w*64+64); A[2][8] hoisted; B from W2b (L2);
//       relu+Wout in-register, shfl_xor reduce, partial[] combine, store out.
// ---------------------------------------------------------------------------
__global__ __launch_bounds__(256, 3) void mlp_kernel(
    const unsigned short* __restrict__ X1b, const unsigned short* __restrict__ W1b,
    const unsigned short* __restrict__ W2b,
    const float* __restrict__ b1, const float* __restrict__ b2,
    const float* __restrict__ Wout, const float* __restrict__ bout,
    float* __restrict__ out)
{
    const int tid  = threadIdx.x;
    const int lane = tid & 63;
    const int wave = tid >> 6;
    const int quad = lane >> 4;
    const int l16  = lane & 15;
    const int pos0 = blockIdx.x * 32;

    __shared__ __align__(16) unsigned short h1s[32 * 256];   // 16 KB (swizzled)
    __shared__ float partial[4][32];                         // 512 B

    // ---- MLP1 ----
    {
        const int rt  = wave & 1;
        const int chh = wave >> 1;
        const bf16x8 afr = *(const bf16x8*)&X1b[((size_t)pos0 + rt * 16 + l16) * 32 + quad * 8];
        #pragma unroll
        for (int n8 = 0; n8 < 8; ++n8) {
            const int col = chh * 128 + n8 * 16 + l16;
            const bf16x8 bfr = *(const bf16x8*)&W1b[col * 32 + quad * 8];
            f32x4 acc = {0.f, 0.f, 0.f, 0.f};
            acc = __builtin_amdgcn_mfma_f32_16x16x32_bf16(afr, bfr, acc, 0, 0, 0);
            const float bb = b1[col];
            #pragma unroll
            for (int r = 0; r < 4; ++r) {
                const int row = rt * 16 + quad * 4 + r;
                *(unsigned short*)((char*)h1s + h1_byte(row, col * 2)) =
                    f2bf(fmaxf(acc[r] + bb, 0.f));
            }
        }
    }
    __syncthreads();

    // ---- MLP2 + out ----
    bf16x8 A[2][8];
    #pragma unroll
    for (int rt2 = 0; rt2 < 2; ++rt2)
        #pragma unroll
        for (int ks = 0; ks < 8; ++ks)
            A[rt2][ks] = *(const bf16x8*)((const char*)h1s +
                           h1_byte(rt2 * 16 + l16, ks * 64 + quad * 16));

    float rsum[2][4] = {};
    #pragma unroll
    for (int i = 0; i < 4; ++i) {
        const int col = (wave * 4 + i) * 16 + l16;
        const unsigned short* wr = W2b + (size_t)col * HIDp + quad * 8;
        bf16x8 Bf[8];
        #pragma unroll
        for (int ks = 0; ks < 8; ++ks)
            Bf[ks] = *(const bf16x8*)(wr + ks * 32);
        const float bb = b2[col];
        const float wo = Wout[col];
        #pragma unroll
        for (int rt2 = 0; rt2 < 2; ++rt2) {
            f32x4 acc = {0.f, 0.f, 0.f, 0.f};
            #pragma unroll
            for (int ks = 0; ks < 8; ++ks)
                acc = __builtin_amdgcn_mfma_f32_16x16x32_bf16(A[rt2][ks], Bf[ks], acc, 0, 0, 0);
            #pragma unroll
            for (int r = 0; r < 4; ++r)
                rsum[rt2][r] += fmaxf(acc[r] + bb, 0.f) * wo;
        }
    }

    #pragma unroll
    for (int off = 1; off < 16; off <<= 1)
        #pragma unroll
        for (int rt2 = 0; rt2 < 2; ++rt2)
            #pragma unroll
            for (int r = 0; r < 4; ++r)
                rsum[rt2][r] += __shfl_xor(rsum[rt2][r], off);

    if (l16 == 0) {
        #pragma unroll
        for (int rt2 = 0; rt2 < 2; ++rt2)
            #pragma unroll
            for (int r = 0; r < 4; ++r)
                partial[wave][rt2 * 16 + quad * 4 + r] = rsum[rt2][r];
    }
    __syncthreads();

    if (tid < 32) {
        out[pos0 + tid] = partial[0][tid] + partial[1][tid]
                        + partial[2][tid] + partial[3][tid] + bout[0];
    }
}

extern "C" void kernel_launch(void* const* d_in, const int* in_sizes, int n_in,
                              void* d_out, int out_size, void* d_ws, size_t ws_size,
                              hipStream_t stream) {
    const float* state  = (const float*)d_in[0];
    const float* action = (const float*)d_in[1];
    const float* Wk     = (const float*)d_in[2];
    const float* Wq     = (const float*)d_in[3];
    const float* Wv     = (const float*)d_in[4];
    const float* W1     = (const float*)d_in[5];
    const float* b1     = (const float*)d_in[6];
    const float* W2     = (const float*)d_in[7];
    const float* b2     = (const float*)d_in[8];
    const float* Wout   = (const float*)d_in[9];
    const float* bout   = (const float*)d_in[10];
    float* out = (float*)d_out;

    char* ws = (char*)d_ws;
    unsigned short* W1b = (unsigned short*)(ws);                  // 16 KB
    unsigned short* W2b = (unsigned short*)(ws + 16384);          // 128 KB
    unsigned short* X1b = (unsigned short*)(ws + 16384 + 131072); // 2 MB

    attn_prep_kernel<<<1024 + 96, 256, 0, stream>>>(state, action, Wk, Wq, Wv,
                                                    W1, W2, W1b, W2b, X1b);
    mlp_kernel<<<(Bp * Tp) / 32, 256, 0, stream>>>(X1b, W1b, W2b, b1, b2,
                                                   Wout, bout, out);
}

// Round 4
// 99.359 us; speedup vs baseline: 1.2089x; 1.0200x over previous
//
#include <hip/hip_runtime.h>
#include <math.h>

#define Bp 256
#define Tp 128
#define SDp 8
#define ADp 2
#define Hp 3
#define Kp 4
#define HIDp 256
#define QDp (SDp + ADp)       // 10
#define X1Dp (Hp * Kp + QDp)  // 22  (row padded to 32 bf16 = 64 B)
#define QKLD 20               // qk row stride (floats): t_loc*20 % 32 distinct -> conflict-free
#define LOG2E 1.4426950408889634f

typedef short bf16x8 __attribute__((ext_vector_type(8)));
typedef float f32x4  __attribute__((ext_vector_type(4)));

__device__ __forceinline__ unsigned short f2bf(float f) {
    unsigned u = __float_as_uint(f);
    unsigned r = (u + 0x7FFFu + ((u >> 16) & 1u)) >> 16;
    return (unsigned short)r;
}

// h1 LDS: row stride 512 B, XOR bits 4-6 with row&7 -> conflict-free b128 col reads
__device__ __forceinline__ unsigned h1_byte(int row, int colbytes) {
    return (((unsigned)row << 9) + (unsigned)colbytes) ^ ((unsigned)(row & 7) << 4);
}
// X1s LDS: row stride 64 B, XOR byte 4-5 with row bits 1-2:
// rows 0..7 -> dword-banks {0,16,4,20,8,24,12,28}: conflict-free b128 A-frag reads
__device__ __forceinline__ unsigned x1_byte(int row, int colbytes) {
    return ((unsigned)row << 6) + ((unsigned)colbytes ^ (((unsigned)row & 6u) << 3));
}

// ---------------------------------------------------------------------------
// prep: one-time W1/W2 f32 -> bf16 (96 blocks, ~1.5 us).
// ---------------------------------------------------------------------------
__global__ __launch_bounds__(256) void prep_kernel(
    const float* __restrict__ W1, const float* __restrict__ W2,
    unsigned short* __restrict__ W1b, unsigned short* __restrict__ W2b)
{
    const int bid = blockIdx.x;
    const int tid = threadIdx.x;
    if (bid < 64) {                       // W2 -> bf16 (65536 elems)
        const int i = bid * 1024 + tid * 4;
        const float4 v = *(const float4*)(W2 + i);
        ushort4 o;
        o.x = f2bf(v.x); o.y = f2bf(v.y); o.z = f2bf(v.z); o.w = f2bf(v.w);
        *(ushort4*)(W2b + i) = o;
    } else {                              // W1 -> bf16, 32-col padded rows
        const int i = (bid - 64) * 256 + tid;   // 0..8191
        const int r = i >> 5, c = i & 31;
        W1b[i] = (c < X1Dp) ? f2bf(W1[r * X1Dp + c]) : (unsigned short)0;
    }
}

// ---------------------------------------------------------------------------
// main (fused): 1024 blocks x 256 threads, 32 positions/block, LDS ~24 KB
// -> 4 blocks/CU; attention VALU overlaps MLP MFMA/memory across blocks.
// Phase A  attention: tid = t_loc*8 + jo; qkp precomputed per t by 32 threads;
//          j-loop 16 iters, bank-rotated; shfl_xor(1,2,4) combine; jo==0
//          lanes finalize and write X1 row (bf16, swizzled) to LDS.
// Phase B  MLP1 MFMA: wave -> (row-tile, col-half); B-frags from W1b (L2);
//          h1 bf16 -> swizzled LDS.
// Phase C  MLP2: wave owns 64 cols; A[2][8] hoisted from h1s; B from W2b (L2);
//          relu+Wout in-register; shfl_xor reduce; partial[] combine; out.
// ---------------------------------------------------------------------------
__global__ __launch_bounds__(256, 4) void main_kernel(
    const float* __restrict__ state, const float* __restrict__ action,
    const float* __restrict__ Wk, const float* __restrict__ Wq,
    const float* __restrict__ Wv,
    const unsigned short* __restrict__ W1b, const unsigned short* __restrict__ W2b,
    const float* __restrict__ b1, const float* __restrict__ b2,
    const float* __restrict__ Wout, const float* __restrict__ bout,
    float* __restrict__ out)
{
    const int bid   = blockIdx.x;
    const int batch = bid >> 2;
    const int t0    = (bid & 3) * 32;
    const int tid   = threadIdx.x;
    const int lane  = tid & 63;
    const int wave  = tid >> 6;
    const int quad  = lane >> 4;
    const int l16   = lane & 15;
    const int t_loc = tid >> 3;
    const int jo    = tid & 7;
    const int t     = t0 + t_loc;

    __shared__ float4 s4[Tp];                                // 2 KB
    __shared__ float  wq[Hp * Kp * QDp];                     // 480 B
    __shared__ float  wk[Hp * Kp * Kp];                      // 192 B
    __shared__ float  wv[Hp * Kp * Kp];                      // 192 B
    __shared__ float  qk[32 * QKLD];                         // 2.5 KB
    __shared__ __align__(16) unsigned short X1s[32 * 32];    // 2 KB (swizzled)
    __shared__ __align__(16) unsigned short h1s[32 * 256];   // 16 KB (swizzled)
    __shared__ float partial[4][32];                         // 512 B

    // ---- stage batch state + small weights ----
    if (tid < Tp)
        s4[tid] = ((const float4*)(state + (size_t)batch * Tp * SDp))[tid * 2];
    if (tid >= Tp && tid < Tp + Hp * Kp * QDp)
        wq[tid - Tp] = Wq[tid - Tp];
    if (tid < Hp * Kp * Kp) { wk[tid] = Wk[tid]; wv[tid] = Wv[tid]; }
    __syncthreads();

    // ---- phase A1: per-t precompute (32 threads) ----
    if (tid < 32) {
        const int tt = t0 + tid;
        const float* srow = state + ((size_t)batch * Tp + tt) * SDp;
        float qs[QDp];
        {
            const float4 v0 = *(const float4*)srow;
            const float4 v1 = *(const float4*)(srow + 4);
            qs[0]=v0.x; qs[1]=v0.y; qs[2]=v0.z; qs[3]=v0.w;
            qs[4]=v1.x; qs[5]=v1.y; qs[6]=v1.z; qs[7]=v1.w;
            const float* arow = action + ((size_t)batch * Tp + tt) * ADp;
            qs[8] = arow[0]; qs[9] = arow[1];
        }
        float q[Hp * Kp];
        #pragma unroll
        for (int r = 0; r < Hp * Kp; ++r) {
            float a = 0.f;
            #pragma unroll
            for (int d = 0; d < QDp; ++d) a += qs[d] * wq[r * QDp + d];
            q[r] = a;
        }
        float* qrow = &qk[tid * QKLD];
        const float4 st = s4[tt];
        #pragma unroll
        for (int h = 0; h < Hp; ++h) {
            float p[4];
            #pragma unroll
            for (int c = 0; c < Kp; ++c) {
                float a = 0.f;
                #pragma unroll
                for (int k = 0; k < Kp; ++k) a += q[h * Kp + k] * wk[(h * Kp + k) * Kp + c];
                p[c] = 0.5f * LOG2E * a;
                qrow[h * 4 + c] = p[c];
            }
            qrow[12 + h] = st.x * p[0] + st.y * p[1] + st.z * p[2] + st.w * p[3];
        }
        #pragma unroll
        for (int i = 0; i < 5; ++i) {
            const unsigned u = (unsigned)f2bf(qs[2*i]) | ((unsigned)f2bf(qs[2*i+1]) << 16);
            qrow[15 + i] = __uint_as_float(u);
        }
    }
    __syncthreads();

    // ---- phase A2: j-loop (all 256 threads) ----
    float rq[20];
    #pragma unroll
    for (int i = 0; i < 5; ++i)
        *(float4*)&rq[i * 4] = *(const float4*)&qk[t_loc * QKLD + i * 4];

    float l[Hp] = {0.f, 0.f, 0.f};
    float ac[Hp][4] = {};
    #pragma unroll
    for (int i = 0; i < 16; ++i) {
        const int j = (jo << 4) | ((i + jo) & 15);   // rotated: conflict-free banks
        const float4 sj = s4[j];
        #pragma unroll
        for (int h = 0; h < Hp; ++h) {
            const float d = sj.x * rq[h*4] + sj.y * rq[h*4+1]
                          + sj.z * rq[h*4+2] + sj.w * rq[h*4+3] - rq[12 + h];
            const float e = (j == t) ? 0.f : __builtin_amdgcn_exp2f(d);
            l[h] += e;
            ac[h][0] += e * sj.x; ac[h][1] += e * sj.y;
            ac[h][2] += e * sj.z; ac[h][3] += e * sj.w;
        }
    }
    #pragma unroll
    for (int off = 1; off < 8; off <<= 1) {
        #pragma unroll
        for (int h = 0; h < Hp; ++h) {
            l[h] += __shfl_xor(l[h], off);
            #pragma unroll
            for (int c = 0; c < Kp; ++c) ac[h][c] += __shfl_xor(ac[h][c], off);
        }
    }

    if (jo == 0) {
        const float4 st = s4[t];
        unsigned short rowb[32] __attribute__((aligned(16)));
        #pragma unroll
        for (int h = 0; h < Hp; ++h) {
            const float inv = 1.f / l[h];
            const float rb0 = ac[h][0] * inv - st.x;
            const float rb1 = ac[h][1] * inv - st.y;
            const float rb2 = ac[h][2] * inv - st.z;
            const float rb3 = ac[h][3] * inv - st.w;
            #pragma unroll
            for (int k = 0; k < Kp; ++k) {
                const int r = h * Kp + k;
                rowb[r] = f2bf(rb0 * wv[r*4] + rb1 * wv[r*4+1] + rb2 * wv[r*4+2] + rb3 * wv[r*4+3]);
            }
        }
        #pragma unroll
        for (int i = 0; i < 5; ++i) {
            const unsigned u = __float_as_uint(rq[15 + i]);
            rowb[12 + 2*i] = (unsigned short)(u & 0xffffu);
            rowb[13 + 2*i] = (unsigned short)(u >> 16);
        }
        #pragma unroll
        for (int i = X1Dp; i < 32; ++i) rowb[i] = 0;

        const uint4* srcv = (const uint4*)rowb;
        #pragma unroll
        for (int i = 0; i < 4; ++i)
            *(uint4*)((char*)X1s + x1_byte(t_loc, i * 16)) = srcv[i];
    }
    __syncthreads();

    // ---- phase B: MLP1 (wave -> row-tile rt, col-half chh) ----
    {
        const int rt  = wave & 1;
        const int chh = wave >> 1;
        const bf16x8 afr = *(const bf16x8*)((const char*)X1s +
                             x1_byte(rt * 16 + l16, quad * 16));
        #pragma unroll
        for (int n8 = 0; n8 < 8; ++n8) {
            const int col = chh * 128 + n8 * 16 + l16;
            const bf16x8 bfr = *(const bf16x8*)&W1b[col * 32 + quad * 8];
            f32x4 acc = {0.f, 0.f, 0.f, 0.f};
            acc = __builtin_amdgcn_mfma_f32_16x16x32_bf16(afr, bfr, acc, 0, 0, 0);
            const float bb = b1[col];
            #pragma unroll
            for (int r = 0; r < 4; ++r) {
                const int row = rt * 16 + quad * 4 + r;
                *(unsigned short*)((char*)h1s + h1_byte(row, col * 2)) =
                    f2bf(fmaxf(acc[r] + bb, 0.f));
            }
        }
    }
    __syncthreads();

    // ---- phase C: MLP2 + out (wave owns cols [wave*64, wave*64+64)) ----
    bf16x8 A[2][8];
    #pragma unroll
    for (int rt2 = 0; rt2 < 2; ++rt2)
        #pragma unroll
        for (int ks = 0; ks < 8; ++ks)
            A[rt2][ks] = *(const bf16x8*)((const char*)h1s +
                           h1_byte(rt2 * 16 + l16, ks * 64 + quad * 16));

    float rsum[2][4] = {};
    #pragma unroll
    for (int i = 0; i < 4; ++i) {
        const int col = (wave * 4 + i) * 16 + l16;
        const unsigned short* wr = W2b + (size_t)col * HIDp + quad * 8;
        bf16x8 Bf[8];
        #pragma unroll
        for (int ks = 0; ks < 8; ++ks)
            Bf[ks] = *(const bf16x8*)(wr + ks * 32);
        const float bb = b2[col];
        const float wo = Wout[col];
        #pragma unroll
        for (int rt2 = 0; rt2 < 2; ++rt2) {
            f32x4 acc = {0.f, 0.f, 0.f, 0.f};
            #pragma unroll
            for (int ks = 0; ks < 8; ++ks)
                acc = __builtin_amdgcn_mfma_f32_16x16x32_bf16(A[rt2][ks], Bf[ks], acc, 0, 0, 0);
            #pragma unroll
            for (int r = 0; r < 4; ++r)
                rsum[rt2][r] += fmaxf(acc[r] + bb, 0.f) * wo;
        }
    }

    #pragma unroll
    for (int off = 1; off < 16; off <<= 1)
        #pragma unroll
        for (int rt2 = 0; rt2 < 2; ++rt2)
            #pragma unroll
            for (int r = 0; r < 4; ++r)
                rsum[rt2][r] += __shfl_xor(rsum[rt2][r], off);

    if (l16 == 0) {
        #pragma unroll
        for (int rt2 = 0; rt2 < 2; ++rt2)
            #pragma unroll
            for (int r = 0; r < 4; ++r)
                partial[wave][rt2 * 16 + quad * 4 + r] = rsum[rt2][r];
    }
    __syncthreads();

    if (tid < 32) {
        out[(size_t)batch * Tp + t0 + tid] =
            partial[0][tid] + partial[1][tid] + partial[2][tid]
          + partial[3][tid] + bout[0];
    }
}

extern "C" void kernel_launch(void* const* d_in, const int* in_sizes, int n_in,
                              void* d_out, int out_size, void* d_ws, size_t ws_size,
                              hipStream_t stream) {
    const float* state  = (const float*)d_in[0];
    const float* action = (const float*)d_in[1];
    const float* Wk     = (const float*)d_in[2];
    const float* Wq     = (const float*)d_in[3];
    const float* Wv     = (const float*)d_in[4];
    const float* W1     = (const float*)d_in[5];
    const float* b1     = (const float*)d_in[6];
    const float* W2     = (const float*)d_in[7];
    const float* b2     = (const float*)d_in[8];
    const float* Wout   = (const float*)d_in[9];
    const float* bout   = (const float*)d_in[10];
    float* out = (float*)d_out;

    char* ws = (char*)d_ws;
    unsigned short* W1b = (unsigned short*)(ws);           // 16 KB
    unsigned short* W2b = (unsigned short*)(ws + 16384);   // 128 KB

    prep_kernel<<<96, 256, 0, stream>>>(W1, W2, W1b, W2b);
    main_kernel<<<4 * Bp, 256, 0, stream>>>(state, action, Wk, Wq, Wv,
                                            W1b, W2b, b1, b2, Wout, bout, out);
}